// Round 8
// baseline (34.379 us; speedup 1.0000x reference)
//
#include <hip/hip_runtime.h>
#include <math.h>

#define HS 64
#define WS 208
#define HF 128
#define WF 416
#define NS (HS * WS)   // 13312
#define KH 20
#define KS 41
#define KK (KS * KS)   // 1681

// align_corners grid: f32 coords exactly as _resize_ac (arange(f32) * (f32(in-1)/f32(out-1))).
__device__ __forceinline__ void ac_idx(int o, int inN, float sc, int& i0, int& i1, float& w) {
#pragma clang fp contract(off)
    float s = (float)o * sc;
    float f = floorf(s);
    i0 = (int)f;
    i1 = min(i0 + 1, inN - 1);
    w = s - f;
}

// k_down: bit-faithful f32 resize of R -> ray4 (padded float4 triples) and of X ->
// normalized dir4; thread 0 also computes the f32 temperature.
__global__ void k_down(const float* __restrict__ R, const float* __restrict__ X,
                       const int* __restrict__ prog,
                       float4* __restrict__ ray4, float4* __restrict__ dir4,
                       float* __restrict__ tbuf) {
#pragma clang fp contract(off)
    int n = blockIdx.x * blockDim.x + threadIdx.x;
    if (n >= NS) return;
    if (n == 0) {
        double T64 = fmax(1e-8, 1e-4 / exp(0.1 * (double)prog[0]));
        tbuf[0] = (float)T64;   // same bits as np.float32(max(1e-8, 1e-4/exp(...)))
    }
    int y = n / WS, x = n - y * WS;
    int y0, y1, x0, x1; float wy, wx;
    ac_idx(y, HF, 127.0f / 63.0f, y0, y1, wy);
    ac_idx(x, WF, 415.0f / 207.0f, x0, x1, wx);
    float omwy = 1.0f - wy, omwx = 1.0f - wx;
    float r[3], d[3];
#pragma unroll
    for (int c = 0; c < 3; ++c) {
        const float* p = R + c * (HF * WF);
        float v00 = p[y0 * WF + x0], v10 = p[y1 * WF + x0];
        float v01 = p[y0 * WF + x1], v11 = p[y1 * WF + x1];
        float a0 = v00 * omwy; float b0 = v10 * wy; float t0 = a0 + b0;
        float a1 = v01 * omwy; float b1 = v11 * wy; float t1 = a1 + b1;
        float c0 = t0 * omwx; float c1 = t1 * wx;
        r[c] = c0 + c1;
        const float* q = X + c * (HF * WF);
        float u00 = q[y0 * WF + x0], u10 = q[y1 * WF + x0];
        float u01 = q[y0 * WF + x1], u11 = q[y1 * WF + x1];
        float e0 = u00 * omwy; float f0 = u10 * wy; float s0 = e0 + f0;
        float e1 = u01 * omwy; float f1 = u11 * wy; float s1 = e1 + f1;
        float g0 = s0 * omwx; float g1 = s1 * wx;
        d[c] = g0 + g1;
    }
    float q0 = d[0] * d[0]; float q1 = d[1] * d[1]; float q2 = d[2] * d[2];
    float ssq = (q0 + q1) + q2;
    float nrm = (float)sqrt((double)ssq);   // correctly-rounded f32 sqrt
    ray4[n] = make_float4(r[0], r[1], r[2], 0.0f);
    dir4[n] = make_float4(d[0] / nrm, d[1] / nrm, d[2] / nrm, 0.0f);
}

// One BLOCK (256 threads) per pixel, ROW-ALIGNED mapping: thread t -> (rt=t/41, ct=t%41),
// iteration j covers window rows 6j..6j+5 -> constant address stride 6*WS (no carry
// logic; all 7 loads issue upfront). rt==6 threads (t>=246) are dead (rows would
// duplicate); j=6 live iff rt<5 (row 36+rt <= 40).
__global__ __launch_bounds__(256) void k_main(const float4* __restrict__ ray4,
                                              const float4* __restrict__ dir4,
                                              const float* __restrict__ tbuf,
                                              float* __restrict__ xn, float* __restrict__ yn) {
#pragma clang fp contract(off)
    int pix = blockIdx.x;
    int tid = (int)threadIdx.x;
    int lane = tid & 63;
    int wid = tid >> 6;
    int h = pix / WS, w = pix - h * WS;
    int srow = min(max(h - KH, 0), HS - 1 - 2 * KH);
    int scol = min(max(w - KH, 0), WS - 1 - 2 * KH);

    float4 dv = dir4[pix];
    float d0 = dv.x, d1 = dv.y, d2 = dv.z;
    float Tf = tbuf[0];

    int rt = (tid * 25) >> 10;         // exact floor(tid/41) for tid<256
    int ct = tid - rt * KS;
    bool act = rt < 6;                 // 246 active threads
    int off = (srow + rt) * WS + scol + ct;

    // Pass 1: raw logits, bit-exact ((p0+p1)+p2), running max; constant stride.
    float lg[7];
    float m = -INFINITY;
#pragma unroll
    for (int j = 0; j < 6; ++j) {
        float l = -INFINITY;
        if (act) {
            float4 v = ray4[off];
            float p0 = d0 * v.x; float p1 = d1 * v.y; float p2 = d2 * v.z;
            l = (p0 + p1) + p2;
        }
        lg[j] = l;
        m = fmaxf(m, l);
        off += 6 * WS;
    }
    {   // j=6: rows 36..40 -> live iff rt < 5
        float l = -INFINITY;
        if (rt < 5) {
            float4 v = ray4[off];
            float p0 = d0 * v.x; float p1 = d1 * v.y; float p2 = d2 * v.z;
            l = (p0 + p1) + p2;
        }
        lg[6] = l;
        m = fmaxf(m, l);
    }
#pragma unroll
    for (int s = 1; s < 64; s <<= 1) m = fmaxf(m, __shfl_xor(m, s));

    __shared__ float smax[4];
    __shared__ float ssum[4][3];
    if (lane == 0) smax[wid] = m;
    __syncthreads();
    m = fmaxf(fmaxf(smax[0], smax[1]), fmaxf(smax[2], smax[3]));

    float zm = m / Tf;                 // monotone div: == ref's max-of-(l/T)
    float thresh = m - 0.004f;         // below: z-zm < -108 -> f32 weight exactly 0

    // Pass 2: row coordinate = srow+rt+6j (incremental +6.0f), col constant.
    float se = 0.f, sr = 0.f, sc = 0.f;
    float fj = (float)(srow + rt);
    float fc = (float)(scol + ct);
#pragma unroll
    for (int j = 0; j < 7; ++j) {
        bool a = lg[j] > thresh;       // dead lanes hold -INF -> false
        if (__ballot(a)) {
            float z = lg[j] / Tf;      // bit-identical to ref's logits/T
            float arg = (z - zm) * 1.442695040888963f;
            float e = a ? __builtin_amdgcn_exp2f(arg) : 0.0f;
            se += e;
            sr += e * fj;
            sc += e * fc;
        }
        fj += 6.0f;
    }
#pragma unroll
    for (int s = 1; s < 64; s <<= 1) {
        se += __shfl_xor(se, s);
        sr += __shfl_xor(sr, s);
        sc += __shfl_xor(sc, s);
    }
    if (lane == 0) { ssum[wid][0] = se; ssum[wid][1] = sr; ssum[wid][2] = sc; }
    __syncthreads();
    if (tid == 0) {
        float SE = (ssum[0][0] + ssum[1][0]) + (ssum[2][0] + ssum[3][0]);
        float SR = (ssum[0][1] + ssum[1][1]) + (ssum[2][1] + ssum[3][1]);
        float SC = (ssum[0][2] + ssum[1][2]) + (ssum[2][2] + ssum[3][2]);
        double ix = (double)SR / (double)SE, iy = (double)SC / (double)SE;
        xn[pix] = (float)(2.0 * ix / (double)(HS - 1) - 1.0);
        yn[pix] = (float)(2.0 * iy / (double)(WS - 1) - 1.0);
    }
}

// Bilinear upsample (align_corners) of (Yn, Xn) to full res, interleaved channels.
__global__ void k_up(const float* __restrict__ xn, const float* __restrict__ yn,
                     float* __restrict__ out) {
#pragma clang fp contract(off)
    int i = blockIdx.x * blockDim.x + threadIdx.x;
    if (i >= HF * WF) return;
    int hh = i / WF, ww = i - hh * WF;
    int y0, y1, x0, x1; float wy, wx;
    ac_idx(hh, HS, 63.0f / 127.0f, y0, y1, wy);
    ac_idx(ww, WS, 207.0f / 415.0f, x0, x1, wx);
    float omwy = 1.0f - wy, omwx = 1.0f - wx;
    float a0, b0, t0, t1;
    a0 = xn[y0 * WS + x0] * omwy; b0 = xn[y1 * WS + x0] * wy; t0 = a0 + b0;
    a0 = xn[y0 * WS + x1] * omwy; b0 = xn[y1 * WS + x1] * wy; t1 = a0 + b0;
    float bx = t0 * omwx + t1 * wx;     // Xn upsampled
    a0 = yn[y0 * WS + x0] * omwy; b0 = yn[y1 * WS + x0] * wy; t0 = a0 + b0;
    a0 = yn[y0 * WS + x1] * omwy; b0 = yn[y1 * WS + x1] * wy; t1 = a0 + b0;
    float ay = t0 * omwx + t1 * wx;     // Yn upsampled
    out[2 * i]     = ay;
    out[2 * i + 1] = bx;
}

extern "C" void kernel_launch(void* const* d_in, const int* in_sizes, int n_in,
                              void* d_out, int out_size, void* d_ws, size_t ws_size,
                              hipStream_t stream) {
    const float* R = (const float*)d_in[0];
    const float* X = (const float*)d_in[1];
    const int* prog = (const int*)d_in[2];
    float4* ray4 = (float4*)d_ws;            // NS float4
    float4* dir4 = ray4 + NS;                // NS float4
    float* xn   = (float*)(dir4 + NS);       // NS
    float* yn   = xn + NS;                   // NS
    float* tbuf = yn + NS;                   // 1
    float* out  = (float*)d_out;

    k_down<<<(NS + 255) / 256, 256, 0, stream>>>(R, X, prog, ray4, dir4, tbuf);
    k_main<<<NS, 256, 0, stream>>>(ray4, dir4, tbuf, xn, yn);   // one block per pixel
    k_up<<<(HF * WF + 255) / 256, 256, 0, stream>>>(xn, yn, out);
}